// Round 12
// baseline (339.948 us; speedup 1.0000x reference)
//
#include <hip/hip_runtime.h>
#include <math.h>

#define NN 50000
#define NE 640000
#define CAP 64   // fixed neighbor-slot capacity; Poisson(12.8) max deg ~40 << 64

typedef short short8 __attribute__((ext_vector_type(8)));   // 8 bf16 (4 VGPRs)
typedef float f32x4  __attribute__((ext_vector_type(4)));   // MFMA accumulator

// ---- bf16 helpers (RNE pack, cheap unpack) ----------------------------------
__device__ __forceinline__ unsigned bfr(float f) {
    unsigned u = __float_as_uint(f);
    return (u + 0x7FFFu + ((u >> 16) & 1u)) >> 16;
}
__device__ __forceinline__ unsigned pk2(float a, float b) { return bfr(a) | (bfr(b) << 16); }
__device__ __forceinline__ float bflo(unsigned u) { return __uint_as_float(u << 16); }
__device__ __forceinline__ float bfhi(unsigned u) { return __uint_as_float(u & 0xFFFF0000u); }

// ---- weight pack into MFMA B-frag layout (bf16) -----------------------------
// B-frag tile (kt,nt): lane = quad*16 + (n&15) holds W'[kt*32+quad*8+j][n].
__device__ __forceinline__ void packOne(const float* Wl, const float* Wr,
                                        unsigned short* wp, int idx,
                                        int CIN, int COUT) {
    int k = idx / COUT, n = idx % COUT;
    float v = (k < CIN) ? Wl[k * COUT + n] : Wr[(k - CIN) * COUT + n];
    int kt = k >> 5, quad = (k >> 3) & 3, j = k & 7;
    int nt = n >> 4, l16 = n & 15;
    int NT = COUT / 16;
    wp[(((kt * NT + nt) * 64) + quad * 16 + l16) * 8 + j] = (unsigned short)bfr(v);
}

// ---- fused prep: bucket-CSR fill + x->bf16 + all weight packs ---------------
// blocks [0,2500): slot fill | [2500,5625): tobf16 | [5625,5889): packs
__global__ __launch_bounds__(256) void
k_prep(const int* __restrict__ src, const int* __restrict__ dst,
       int* __restrict__ cnt, int* __restrict__ nbr,
       const float* __restrict__ x, unsigned* __restrict__ xb,
       const float* Wl0, const float* Wr0, const float* Wl1, const float* Wr1,
       const float* Wl2, const float* Wr2, const float* Wc1,
       unsigned short* wp0, unsigned short* wp1, unsigned short* wp2,
       unsigned short* wpc) {
    const int b = blockIdx.x, t = threadIdx.x;
    if (b < 2500) {
        int e = b * 256 + t;
        if (e < NE) {
            int d = dst[e];
            int p = atomicAdd(&cnt[d], 1);
            if (p < CAP) nbr[d * CAP + p] = src[e];
        }
    } else if (b < 5625) {
        int i = (b - 2500) * 256 + t;          // NN*16 = 800000 float4 groups
        if (i < NN * 16) {
            float4 v = ((const float4*)x)[i];
            ((uint2*)xb)[i] = make_uint2(pk2(v.x, v.y), pk2(v.z, v.w));
        }
    } else {
        int idx = (b - 5625) * 256 + t;
        if (idx < 16384) {                     // 2*64*128
            packOne(Wl0, Wr0, wp0, idx, 64, 128);
        } else if (idx < 49152) {              // + 2*128*128
            packOne(Wl1, Wr1, wp1, idx - 16384, 128, 128);
        } else if (idx < 65536) {              // + 2*128*64
            packOne(Wl2, Wr2, wp2, idx - 49152, 128, 64);
        } else if (idx < 67584) {              // + 64*32 classifier Wc1
            packOne(Wc1, Wc1, wpc, idx - 65536, 64, 32);
        }
    }
}

// ---- shared building blocks for fused layer kernels -------------------------
// Gather-aggregate the block's 128 nodes into LDS (bf16, row stride RPAD).
// Wave handles 32 nodes sequentially (slot prefetch one node ahead); per node:
// quarter-wave per neighbor (R11-verified inner loop), shfl_xor reduce,
// qw==0 writes the bf16 row with the mean scale folded in.
template <int CIN, int RPAD>
__device__ __forceinline__ void
gather_to_lds(short* As, const unsigned short* __restrict__ Xprev,
              const int* __restrict__ nbr, const int* __restrict__ cnt,
              int nb0, int N, int wave, int lane, int qw, int l16) {
    constexpr int PC = CIN / 32;          // uints per lane16 per row: 2 | 4
    const unsigned* xu = (const unsigned*)Xprev;

    int node = nb0 + wave * 32; if (node >= N) node = N - 1;
    int dcur = cnt[node];
    int scur = nbr[node * CAP + lane];

    for (int it = 0; it < 32; ++it) {
        const int deg = dcur;
        const int sl  = scur;
        if (it + 1 < 32) {
            int nn = nb0 + wave * 32 + it + 1; if (nn >= N) nn = N - 1;
            dcur = cnt[nn];
            scur = nbr[nn * CAP + lane];
        }
        const int m = (deg < CAP) ? deg : CAP;
        const int sc = (lane < m) ? sl : 0;

        float a[2 * PC] = {};
#pragma unroll 4
        for (int j = 0; j < m; j += 4) {
            const int n = __shfl(sc, (j + qw) & 63);
            const bool valid = (j + qw) < m;
            if (PC == 2) {
                const uint2 u = *(const uint2*)(xu + (size_t)n * 32 + l16 * 2);
                if (valid) {
                    a[0] += bflo(u.x); a[1] += bfhi(u.x);
                    a[2] += bflo(u.y); a[3] += bfhi(u.y);
                }
            } else {
                const uint4 u = *(const uint4*)(xu + (size_t)n * 64 + l16 * 4);
                if (valid) {
                    a[0] += bflo(u.x); a[1] += bfhi(u.x);
                    a[2] += bflo(u.y); a[3] += bfhi(u.y);
                    a[4] += bflo(u.z); a[5] += bfhi(u.z);
                    a[6] += bflo(u.w); a[7] += bfhi(u.w);
                }
            }
        }

#pragma unroll
        for (int c = 0; c < 2 * PC; ++c) {
            a[c] += __shfl_xor(a[c], 16);
            a[c] += __shfl_xor(a[c], 32);
        }

        if (qw == 0) {
            const float di = 1.0f / (float)((deg > 1) ? deg : 1);
            const int row = wave * 32 + it;
            if (PC == 2) {
                uint2 o = make_uint2(pk2(a[0] * di, a[1] * di), pk2(a[2] * di, a[3] * di));
                *(uint2*)&As[row * RPAD + l16 * 4] = o;
            } else {
                uint4 o = make_uint4(pk2(a[0] * di, a[1] * di), pk2(a[2] * di, a[3] * di),
                                     pk2(a[4] * di, a[5] * di), pk2(a[6] * di, a[7] * di));
                *(uint4*)&As[row * RPAD + l16 * 8] = o;
            }
        }
    }
}

// ---- fused SAGE layer: block aggregates its 128 rows into LDS, then MFMA ----
// out = act( [agg|x] @ [Wl;Wr] + b ). A-frags: agg from LDS, x from global.
// B-frags straight from global packed table (L2-hot, shared by all blocks).
template <int CIN, int COUT, bool RELU>
__global__ __launch_bounds__(256, 2) void
k_layer(const unsigned short* __restrict__ Xprev, const int* __restrict__ nbr,
        const int* __restrict__ cnt, const unsigned short* __restrict__ Wpack,
        const float* __restrict__ bias, unsigned short* __restrict__ outp, int N) {
    constexpr int KT = (2 * CIN) / 32;
    constexpr int NT = COUT / 16;
    constexpr int RPAD = CIN + 10;       // shorts; bank pattern 5l+4q -> <=2-way

    __shared__ __align__(16) short As[128 * RPAD];

    const int t = threadIdx.x, wave = t >> 6, lane = t & 63;
    const int qw = lane >> 4, l16 = lane & 15;
    const int nb0 = blockIdx.x * 128;

    gather_to_lds<CIN, RPAD>(As, Xprev, nbr, cnt, nb0, N, wave, lane, qw, l16);
    __syncthreads();

    const int row_base = nb0 + wave * 32;
    int r0g = row_base + l16;      if (r0g >= N) r0g = N - 1;
    int r1g = row_base + 16 + l16; if (r1g >= N) r1g = N - 1;
    const int l0 = wave * 32 + l16;
    const int l1 = wave * 32 + 16 + l16;

    f32x4 acc[2][NT] = {};

    for (int kt = 0; kt < KT; ++kt) {
        short8 a0, a1;
        if (kt < KT / 2) {
            const int kb = kt * 32 + qw * 8;
            a0 = *(const short8*)&As[l0 * RPAD + kb];
            a1 = *(const short8*)&As[l1 * RPAD + kb];
        } else {
            const int kb = kt * 32 - CIN + qw * 8;
            a0 = *(const short8*)(Xprev + (size_t)r0g * CIN + kb);
            a1 = *(const short8*)(Xprev + (size_t)r1g * CIN + kb);
        }
#pragma unroll
        for (int nt = 0; nt < NT; ++nt) {
            const short8 bfrag = *(const short8*)(Wpack + (size_t)((kt * NT + nt) * 64 + lane) * 8);
            acc[0][nt] = __builtin_amdgcn_mfma_f32_16x16x32_bf16(a0, bfrag, acc[0][nt], 0, 0, 0);
            acc[1][nt] = __builtin_amdgcn_mfma_f32_16x16x32_bf16(a1, bfrag, acc[1][nt], 0, 0, 0);
        }
    }

#pragma unroll
    for (int nt = 0; nt < NT; ++nt) {
        const int col = nt * 16 + l16;
        const float bb = bias[col];
#pragma unroll
        for (int s = 0; s < 2; ++s) {
#pragma unroll
            for (int rg = 0; rg < 4; ++rg) {
                int row = row_base + s * 16 + qw * 4 + rg;
                if (row < N) {
                    float v = acc[s][nt][rg] + bb;
                    if (RELU) v = fmaxf(v, 0.f);
                    outp[(size_t)row * COUT + col] = (unsigned short)bfr(v);
                }
            }
        }
    }
}

// ---- fused layer 2 + classifier ---------------------------------------------
// Same structure (CIN=128, COUT=64, no relu), then h routed through LDS
// (C-layout -> A-layout), 8 classifier MFMAs (Wc1 frags from global), +bc1,
// ReLU, dot Wc2, 16-lane reduce, +bc2, sigmoid -> out.
__global__ __launch_bounds__(256, 2) void
k_layer_cls(const unsigned short* __restrict__ Xprev, const int* __restrict__ nbr,
            const int* __restrict__ cnt, const unsigned short* __restrict__ Wpack,
            const unsigned short* __restrict__ WpackC, const float* __restrict__ bias,
            const float* __restrict__ bc1, const float* __restrict__ Wc2,
            const float* __restrict__ bc2, float* __restrict__ out, int N) {
    constexpr int CIN = 128, COUT = 64;
    constexpr int KT = 8, NT = 4;
    constexpr int RPAD = CIN + 10;

    __shared__ __align__(16) short As[128 * RPAD];   // ~34.5 KB
    __shared__ __align__(16) short Hs[8 * 16 * 64];  // 16 KB (wave,strip,row,col)

    const int t = threadIdx.x, wave = t >> 6, lane = t & 63;
    const int qw = lane >> 4, l16 = lane & 15;
    const int nb0 = blockIdx.x * 128;

    gather_to_lds<CIN, RPAD>(As, Xprev, nbr, cnt, nb0, N, wave, lane, qw, l16);
    __syncthreads();

    const int row_base = nb0 + wave * 32;
    int r0g = row_base + l16;      if (r0g >= N) r0g = N - 1;
    int r1g = row_base + 16 + l16; if (r1g >= N) r1g = N - 1;
    const int l0 = wave * 32 + l16;
    const int l1 = wave * 32 + 16 + l16;

    f32x4 acc[2][NT] = {};

    for (int kt = 0; kt < KT; ++kt) {
        short8 a0, a1;
        if (kt < KT / 2) {
            const int kb = kt * 32 + qw * 8;
            a0 = *(const short8*)&As[l0 * RPAD + kb];
            a1 = *(const short8*)&As[l1 * RPAD + kb];
        } else {
            const int kb = kt * 32 - CIN + qw * 8;
            a0 = *(const short8*)(Xprev + (size_t)r0g * CIN + kb);
            a1 = *(const short8*)(Xprev + (size_t)r1g * CIN + kb);
        }
#pragma unroll
        for (int nt = 0; nt < NT; ++nt) {
            const short8 bfrag = *(const short8*)(Wpack + (size_t)((kt * NT + nt) * 64 + lane) * 8);
            acc[0][nt] = __builtin_amdgcn_mfma_f32_16x16x32_bf16(a0, bfrag, acc[0][nt], 0, 0, 0);
            acc[1][nt] = __builtin_amdgcn_mfma_f32_16x16x32_bf16(a1, bfrag, acc[1][nt], 0, 0, 0);
        }
    }

    // h tile (C-layout) -> Hs bf16 (row-major per wave-strip): +b2, no relu
#pragma unroll
    for (int nt = 0; nt < NT; ++nt) {
        const float bb = bias[nt * 16 + l16];
#pragma unroll
        for (int s = 0; s < 2; ++s)
#pragma unroll
            for (int rg = 0; rg < 4; ++rg)
                Hs[(wave * 2 + s) * 1024 + (qw * 4 + rg) * 64 + nt * 16 + l16] =
                    (unsigned short)bfr(acc[s][nt][rg] + bb);
    }
    __syncthreads();   // cross-lane LDS dependency (within-wave strips only, but cheap)

    // classifier GEMM: h(16x64) @ Wc1(64x32); A-frag: m=l16, k=quad*8+j
    f32x4 sacc[2][2] = {};
#pragma unroll
    for (int s = 0; s < 2; ++s)
#pragma unroll
        for (int kt2 = 0; kt2 < 2; ++kt2) {
            const short8 af = *(const short8*)&Hs[(wave * 2 + s) * 1024 + l16 * 64 +
                                                  kt2 * 32 + qw * 8];
#pragma unroll
            for (int nt2 = 0; nt2 < 2; ++nt2) {
                const short8 bf = *(const short8*)(WpackC + (size_t)((kt2 * 2 + nt2) * 64 + lane) * 8);
                sacc[s][nt2] = __builtin_amdgcn_mfma_f32_16x16x32_bf16(af, bf, sacc[s][nt2], 0, 0, 0);
            }
        }

    // +bc1, ReLU, dot Wc2, reduce over 16 cols, +bc2, sigmoid
    const float b1a = bc1[l16], b1b = bc1[16 + l16];
    const float w2a = Wc2[l16], w2b = Wc2[16 + l16];
    const float b2v = bc2[0];
#pragma unroll
    for (int s = 0; s < 2; ++s)
#pragma unroll
        for (int rg = 0; rg < 4; ++rg) {
            float p = fmaxf(sacc[s][0][rg] + b1a, 0.f) * w2a +
                      fmaxf(sacc[s][1][rg] + b1b, 0.f) * w2b;
#pragma unroll
            for (int off = 1; off < 16; off <<= 1) p += __shfl_xor(p, off);
            if (l16 == 0) {
                int row = row_base + s * 16 + qw * 4 + rg;
                if (row < N) out[row] = 1.0f / (1.0f + expf(-(p + b2v)));
            }
        }
}

extern "C" void kernel_launch(void* const* d_in, const int* in_sizes, int n_in,
                              void* d_out, int out_size, void* d_ws, size_t ws_size,
                              hipStream_t stream) {
    const float* x   = (const float*)d_in[0];
    const int*   ei  = (const int*)d_in[1];   // [2, NE] int32
    const int*   src = ei;
    const int*   dst = ei + NE;
    const float* Wl0 = (const float*)d_in[2];
    const float* Wr0 = (const float*)d_in[3];
    const float* b0  = (const float*)d_in[4];
    const float* Wl1 = (const float*)d_in[5];
    const float* Wr1 = (const float*)d_in[6];
    const float* b1  = (const float*)d_in[7];
    const float* Wl2 = (const float*)d_in[8];
    const float* Wr2 = (const float*)d_in[9];
    const float* b2  = (const float*)d_in[10];
    const float* Wc1 = (const float*)d_in[11];
    const float* bc1 = (const float*)d_in[12];
    const float* Wc2 = (const float*)d_in[13];
    const float* bc2 = (const float*)d_in[14];
    float* out = (float*)d_out;

    // workspace layout (bytes):
    //   [0,200K)   cnt  (NN ints)
    //   [256K)     wp0 32K | [352K) wp1 64K | [448K) wp2 32K | [512K) wpc 4K
    //   [1M)       nbr  NN*CAP ints (12.8M)
    //   [16M)      xb   NN*64  bf16 ( 6.4M)
    //   [24M)      h0b  NN*128 bf16 (12.8M)
    //   [40M)      h1b  NN*128 bf16 (12.8M)
    char*  ws   = (char*)d_ws;
    int*   cnt  = (int*)(ws);
    unsigned short* wp0 = (unsigned short*)(ws + (size_t)256 * 1024);
    unsigned short* wp1 = (unsigned short*)(ws + (size_t)352 * 1024);
    unsigned short* wp2 = (unsigned short*)(ws + (size_t)448 * 1024);
    unsigned short* wpc = (unsigned short*)(ws + (size_t)512 * 1024);
    int*   nbr  = (int*)(ws + (size_t)1 * (1 << 20));
    unsigned short* xb  = (unsigned short*)(ws + (size_t)16 * (1 << 20));
    unsigned short* h0b = (unsigned short*)(ws + (size_t)24 * (1 << 20));
    unsigned short* h1b = (unsigned short*)(ws + (size_t)40 * (1 << 20));

    const int B = 256;
    const int LAYER_GRID = (NN + 127) / 128;   // 391 blocks

    // ---- bucket-CSR fill + input/weight conversion (one kernel) ----
    hipMemsetAsync(cnt, 0, (size_t)NN * sizeof(int), stream);
    k_prep<<<5889, B, 0, stream>>>(src, dst, cnt, nbr, x, (unsigned*)xb,
                                   Wl0, Wr0, Wl1, Wr1, Wl2, Wr2, Wc1,
                                   wp0, wp1, wp2, wpc);

    // ---- fused layers (aggregate-in-LDS + MFMA GEMM) ----
    k_layer<64, 128, true><<<LAYER_GRID, B, 0, stream>>>(xb, nbr, cnt, wp0, b0, h0b, NN);
    k_layer<128, 128, true><<<LAYER_GRID, B, 0, stream>>>(h0b, nbr, cnt, wp1, b1, h1b, NN);
    k_layer_cls<<<LAYER_GRID, B, 0, stream>>>(h1b, nbr, cnt, wp2, wpc, b2, bc1, Wc2, bc2,
                                              out, NN);
}

// Round 14
// 231.941 us; speedup vs baseline: 1.4657x; 1.4657x over previous
//
#include <hip/hip_runtime.h>
#include <hip/hip_cooperative_groups.h>
#include <math.h>

namespace cg = cooperative_groups;

#define NN 50000
#define NE 640000
#define CAP 64   // fixed neighbor-slot capacity; Poisson(12.8) max deg ~40 << 64

typedef short short8 __attribute__((ext_vector_type(8)));   // 8 bf16 (4 VGPRs)
typedef float f32x4  __attribute__((ext_vector_type(4)));   // MFMA accumulator

// ---- bf16 helpers (RNE pack, cheap unpack) ----------------------------------
__device__ __forceinline__ unsigned bfr(float f) {
    unsigned u = __float_as_uint(f);
    return (u + 0x7FFFu + ((u >> 16) & 1u)) >> 16;
}
__device__ __forceinline__ unsigned pk2(float a, float b) { return bfr(a) | (bfr(b) << 16); }
__device__ __forceinline__ float bflo(unsigned u) { return __uint_as_float(u << 16); }
__device__ __forceinline__ float bfhi(unsigned u) { return __uint_as_float(u & 0xFFFF0000u); }

// ---- weight pack into MFMA B-frag layout (bf16) -----------------------------
__device__ __forceinline__ void packOne(const float* Wl, const float* Wr,
                                        unsigned short* wp, int idx,
                                        int CIN, int COUT) {
    int k = idx / COUT, n = idx % COUT;
    float v = (k < CIN) ? Wl[k * COUT + n] : Wr[(k - CIN) * COUT + n];
    int kt = k >> 5, quad = (k >> 3) & 3, j = k & 7;
    int nt = n >> 4, l16 = n & 15;
    int NT = COUT / 16;
    wp[(((kt * NT + nt) * 64) + quad * 16 + l16) * 8 + j] = (unsigned short)bfr(v);
}

// ---- device building blocks (grid-stride aware) -----------------------------
template <int LOGC>
__device__ __forceinline__ void
agg_phase(const unsigned* __restrict__ xu, const int* __restrict__ nbr,
          const int* __restrict__ cnt, unsigned* __restrict__ aggu,
          int wgl, int nwave, int lane) {
    constexpr int RU = 1 << (LOGC - 1);   // uints/row: 32 (C=64) | 64 (C=128)
    constexpr int PC = RU / 16;           // uints per lane16: 2 | 4
    const int qw = lane >> 4, l16 = lane & 15;

    for (int gw = wgl; gw < NN; gw += nwave) {
        const int deg = cnt[gw];
        const int m = (deg < CAP) ? deg : CAP;

        int idx = 0;
        if (lane < m) idx = nbr[gw * CAP + lane];

        float a[2 * PC] = {};

#pragma unroll 4
        for (int j = 0; j < m; j += 4) {
            const int n = __shfl(idx, (j + qw) & 63);
            const bool valid = (j + qw) < m;
            if (PC == 2) {
                const uint2 u = *(const uint2*)(xu + (size_t)n * RU + l16 * 2);
                if (valid) {
                    a[0] += bflo(u.x); a[1] += bfhi(u.x);
                    a[2] += bflo(u.y); a[3] += bfhi(u.y);
                }
            } else {
                const uint4 u = *(const uint4*)(xu + (size_t)n * RU + l16 * 4);
                if (valid) {
                    a[0] += bflo(u.x); a[1] += bfhi(u.x);
                    a[2] += bflo(u.y); a[3] += bfhi(u.y);
                    a[4] += bflo(u.z); a[5] += bfhi(u.z);
                    a[6] += bflo(u.w); a[7] += bfhi(u.w);
                }
            }
        }

#pragma unroll
        for (int c = 0; c < 2 * PC; ++c) {
            a[c] += __shfl_xor(a[c], 16);
            a[c] += __shfl_xor(a[c], 32);
        }

        if (qw == 0) {
            const float di = 1.0f / (float)((deg > 1) ? deg : 1);
            if (PC == 2) {
                uint2 o = make_uint2(pk2(a[0] * di, a[1] * di), pk2(a[2] * di, a[3] * di));
                *(uint2*)(aggu + (size_t)gw * RU + l16 * 2) = o;
            } else {
                uint4 o = make_uint4(pk2(a[0] * di, a[1] * di), pk2(a[2] * di, a[3] * di),
                                     pk2(a[4] * di, a[5] * di), pk2(a[6] * di, a[7] * di));
                *(uint4*)(aggu + (size_t)gw * RU + l16 * 4) = o;
            }
        }
    }
}

template <int CIN, int COUT, bool RELU>
__device__ __forceinline__ void
mfma_phase(const unsigned short* __restrict__ Agg, const unsigned short* __restrict__ X,
           const unsigned short* __restrict__ Wpack, const float* __restrict__ bias,
           unsigned short* __restrict__ outp, int blk, int gstride, int wave, int lane) {
    constexpr int KT = (2 * CIN) / 32;
    constexpr int NT = COUT / 16;
    const int quad = lane >> 4, l16 = lane & 15;
    const int NTILE = (NN + 127) / 128;

    for (int tile = blk; tile < NTILE; tile += gstride) {
        const int row_base = tile * 128 + wave * 32;
        int r0 = row_base + l16;      if (r0 >= NN) r0 = NN - 1;
        int r1 = row_base + 16 + l16; if (r1 >= NN) r1 = NN - 1;

        f32x4 acc[2][NT] = {};

        for (int kt = 0; kt < KT; ++kt) {
            const unsigned short* P = (kt < KT / 2) ? Agg : X;
            const int kb = (kt < KT / 2) ? kt * 32 : kt * 32 - CIN;
            const short8 a0 = *(const short8*)(P + (size_t)r0 * CIN + kb + quad * 8);
            const short8 a1 = *(const short8*)(P + (size_t)r1 * CIN + kb + quad * 8);
#pragma unroll
            for (int nt = 0; nt < NT; ++nt) {
                const short8 bfrag = *(const short8*)(Wpack + (size_t)((kt * NT + nt) * 64 + lane) * 8);
                acc[0][nt] = __builtin_amdgcn_mfma_f32_16x16x32_bf16(a0, bfrag, acc[0][nt], 0, 0, 0);
                acc[1][nt] = __builtin_amdgcn_mfma_f32_16x16x32_bf16(a1, bfrag, acc[1][nt], 0, 0, 0);
            }
        }

#pragma unroll
        for (int nt = 0; nt < NT; ++nt) {
            const int col = nt * 16 + l16;
            const float bb = bias[col];
#pragma unroll
            for (int s = 0; s < 2; ++s) {
#pragma unroll
                for (int rg = 0; rg < 4; ++rg) {
                    int row = row_base + s * 16 + quad * 4 + rg;
                    if (row < NN) {
                        float v = acc[s][nt][rg] + bb;
                        if (RELU) v = fmaxf(v, 0.f);
                        outp[(size_t)row * COUT + col] = (unsigned short)bfr(v);
                    }
                }
            }
        }
    }
}

// ---- ONE cooperative kernel (grid-size agnostic) ----------------------------
__global__ __launch_bounds__(256) void
k_all(const int* __restrict__ src, const int* __restrict__ dst,
      const float* __restrict__ x,
      const float* Wl0, const float* Wr0, const float* b0,
      const float* Wl1, const float* Wr1, const float* b1,
      const float* Wl2, const float* Wr2, const float* b2,
      const float* Wc1, const float* bc1, const float* Wc2, const float* bc2,
      int* cnt, int* nbr, unsigned short* xb,
      unsigned short* wp0, unsigned short* wp1, unsigned short* wp2,
      unsigned short* wpc,
      unsigned short* aggb, unsigned short* h0b, unsigned short* h1b,
      float* out) {
    cg::grid_group grid = cg::this_grid();

    __shared__ __align__(16) short Hs[8 * 16 * 64];   // 16 KB (classifier phase)

    const int t = threadIdx.x, b = blockIdx.x;
    const int nthr = gridDim.x * 256;
    const int nwave = nthr >> 6;
    const int gt = b * 256 + t;
    const int wave = t >> 6, lane = t & 63;
    const int wgl = gt >> 6;
    const int quad = lane >> 4, l16 = lane & 15;

    // ---- phase 1: bucket-CSR fill + x->bf16 + weight packs (cnt pre-zeroed) --
    for (int e = gt; e < NE; e += nthr) {
        int d = dst[e];
        int p = atomicAdd(&cnt[d], 1);
        if (p < CAP) nbr[d * CAP + p] = src[e];
    }
    for (int i = gt; i < NN * 16; i += nthr) {
        float4 v = ((const float4*)x)[i];
        ((uint2*)xb)[i] = make_uint2(pk2(v.x, v.y), pk2(v.z, v.w));
    }
    for (int i = gt; i < 67584; i += nthr) {
        if (i < 16384) packOne(Wl0, Wr0, wp0, i, 64, 128);
        else if (i < 49152) packOne(Wl1, Wr1, wp1, i - 16384, 128, 128);
        else if (i < 65536) packOne(Wl2, Wr2, wp2, i - 49152, 128, 64);
        else packOne(Wc1, Wc1, wpc, i - 65536, 64, 32);
    }
    grid.sync();

    // ---- layer 0 ----
    agg_phase<6>((const unsigned*)xb, nbr, cnt, (unsigned*)aggb, wgl, nwave, lane);
    grid.sync();
    mfma_phase<64, 128, true>(aggb, xb, wp0, b0, h0b, b, gridDim.x, wave, lane);
    grid.sync();

    // ---- layer 1 ----
    agg_phase<7>((const unsigned*)h0b, nbr, cnt, (unsigned*)aggb, wgl, nwave, lane);
    grid.sync();
    mfma_phase<128, 128, true>(aggb, h0b, wp1, b1, h1b, b, gridDim.x, wave, lane);
    grid.sync();

    // ---- layer 2 ----
    agg_phase<7>((const unsigned*)h1b, nbr, cnt, (unsigned*)aggb, wgl, nwave, lane);
    grid.sync();

    // ---- layer 2 GEMM + fused classifier ----
    {
        constexpr int CIN = 128, NT = 4, KT = 8;
        const int NTILE = (NN + 127) / 128;

        for (int tile = b; tile < NTILE; tile += gridDim.x) {
            const int row_base = tile * 128 + wave * 32;
            int r0 = row_base + l16;      if (r0 >= NN) r0 = NN - 1;
            int r1 = row_base + 16 + l16; if (r1 >= NN) r1 = NN - 1;

            f32x4 acc[2][NT] = {};

            for (int kt = 0; kt < KT; ++kt) {
                const unsigned short* P = (kt < KT / 2) ? aggb : h1b;
                const int kb = (kt < KT / 2) ? kt * 32 : kt * 32 - CIN;
                const short8 a0 = *(const short8*)(P + (size_t)r0 * CIN + kb + quad * 8);
                const short8 a1 = *(const short8*)(P + (size_t)r1 * CIN + kb + quad * 8);
#pragma unroll
                for (int nt = 0; nt < NT; ++nt) {
                    const short8 bfrag = *(const short8*)(wp2 + (size_t)((kt * NT + nt) * 64 + lane) * 8);
                    acc[0][nt] = __builtin_amdgcn_mfma_f32_16x16x32_bf16(a0, bfrag, acc[0][nt], 0, 0, 0);
                    acc[1][nt] = __builtin_amdgcn_mfma_f32_16x16x32_bf16(a1, bfrag, acc[1][nt], 0, 0, 0);
                }
            }

#pragma unroll
            for (int nt = 0; nt < NT; ++nt) {
                const float bb = b2[nt * 16 + l16];
#pragma unroll
                for (int s = 0; s < 2; ++s)
#pragma unroll
                    for (int rg = 0; rg < 4; ++rg)
                        Hs[(wave * 2 + s) * 1024 + (quad * 4 + rg) * 64 + nt * 16 + l16] =
                            (unsigned short)bfr(acc[s][nt][rg] + bb);
            }
            __syncthreads();

            f32x4 sacc[2][2] = {};
#pragma unroll
            for (int s = 0; s < 2; ++s)
#pragma unroll
                for (int kt2 = 0; kt2 < 2; ++kt2) {
                    const short8 af = *(const short8*)&Hs[(wave * 2 + s) * 1024 + l16 * 64 +
                                                          kt2 * 32 + quad * 8];
#pragma unroll
                    for (int nt2 = 0; nt2 < 2; ++nt2) {
                        const short8 bf = *(const short8*)(wpc + (size_t)((kt2 * 2 + nt2) * 64 + lane) * 8);
                        sacc[s][nt2] = __builtin_amdgcn_mfma_f32_16x16x32_bf16(af, bf, sacc[s][nt2], 0, 0, 0);
                    }
                }

            const float b1a = bc1[l16], b1b = bc1[16 + l16];
            const float w2a = Wc2[l16], w2b = Wc2[16 + l16];
            const float b2v = bc2[0];
#pragma unroll
            for (int s = 0; s < 2; ++s)
#pragma unroll
                for (int rg = 0; rg < 4; ++rg) {
                    float p = fmaxf(sacc[s][0][rg] + b1a, 0.f) * w2a +
                              fmaxf(sacc[s][1][rg] + b1b, 0.f) * w2b;
#pragma unroll
                    for (int off = 1; off < 16; off <<= 1) p += __shfl_xor(p, off);
                    if (l16 == 0) {
                        int row = row_base + s * 16 + quad * 4 + rg;
                        if (row < NN) out[row] = 1.0f / (1.0f + expf(-(p + b2v)));
                    }
                }
            __syncthreads();
        }
    }
}

// ================= R11 fallback kernels (proven at 239 us) ===================
__global__ __launch_bounds__(256) void
k_prep(const int* __restrict__ src, const int* __restrict__ dst,
       int* __restrict__ cnt, int* __restrict__ nbr,
       const float* __restrict__ x, unsigned* __restrict__ xb,
       const float* Wl0, const float* Wr0, const float* Wl1, const float* Wr1,
       const float* Wl2, const float* Wr2, const float* Wc1,
       unsigned short* wp0, unsigned short* wp1, unsigned short* wp2,
       unsigned short* wpc) {
    const int b = blockIdx.x, t = threadIdx.x;
    if (b < 2500) {
        int e = b * 256 + t;
        if (e < NE) {
            int d = dst[e];
            int p = atomicAdd(&cnt[d], 1);
            if (p < CAP) nbr[d * CAP + p] = src[e];
        }
    } else if (b < 5625) {
        int i = (b - 2500) * 256 + t;
        if (i < NN * 16) {
            float4 v = ((const float4*)x)[i];
            ((uint2*)xb)[i] = make_uint2(pk2(v.x, v.y), pk2(v.z, v.w));
        }
    } else {
        int idx = (b - 5625) * 256 + t;
        if (idx < 16384) packOne(Wl0, Wr0, wp0, idx, 64, 128);
        else if (idx < 49152) packOne(Wl1, Wr1, wp1, idx - 16384, 128, 128);
        else if (idx < 65536) packOne(Wl2, Wr2, wp2, idx - 49152, 128, 64);
        else if (idx < 67584) packOne(Wc1, Wc1, wpc, idx - 65536, 64, 32);
    }
}

template <int LOGC>
__global__ __launch_bounds__(256) void
k_aggregate(const unsigned* __restrict__ xu, const int* __restrict__ nbr,
            const int* __restrict__ cnt, unsigned* __restrict__ aggu, int N) {
    const int wgl = (blockIdx.x * 256 + threadIdx.x) >> 6;
    if (wgl >= N) return;
    // single-node version: reuse agg_phase with stride big enough to run once
    agg_phase<LOGC>(xu, nbr, cnt, aggu, wgl, 1 << 30, threadIdx.x & 63);
}

template <int CIN, int COUT, bool RELU>
__global__ __launch_bounds__(256) void
k_mfma(const unsigned short* __restrict__ Agg, const unsigned short* __restrict__ X,
       const unsigned short* __restrict__ Wpack, const float* __restrict__ bias,
       unsigned short* __restrict__ outp, int N) {
    mfma_phase<CIN, COUT, RELU>(Agg, X, Wpack, bias, outp,
                                blockIdx.x, 1 << 30, threadIdx.x >> 6, threadIdx.x & 63);
}

__global__ __launch_bounds__(256) void
k_mfma_cls(const unsigned short* __restrict__ Agg, const unsigned short* __restrict__ X,
           const unsigned short* __restrict__ Wpack, const unsigned short* __restrict__ WpackC,
           const float* __restrict__ bias, const float* __restrict__ bc1,
           const float* __restrict__ Wc2, const float* __restrict__ bc2,
           float* __restrict__ out, int N) {
    constexpr int CIN = 128, NT = 4, KT = 8;

    __shared__ __align__(16) short Hs[8 * 16 * 64];

    const int t = threadIdx.x;
    const int wave = t >> 6, lane = t & 63;
    const int quad = lane >> 4, l16 = lane & 15;

    const int row_base = blockIdx.x * 128 + wave * 32;
    int r0 = row_base + l16;      if (r0 >= N) r0 = N - 1;
    int r1 = row_base + 16 + l16; if (r1 >= N) r1 = N - 1;

    f32x4 acc[2][NT] = {};

    for (int kt = 0; kt < KT; ++kt) {
        const unsigned short* P = (kt < KT / 2) ? Agg : X;
        const int kb = (kt < KT / 2) ? kt * 32 : kt * 32 - CIN;
        const short8 a0 = *(const short8*)(P + (size_t)r0 * CIN + kb + quad * 8);
        const short8 a1 = *(const short8*)(P + (size_t)r1 * CIN + kb + quad * 8);
#pragma unroll
        for (int nt = 0; nt < NT; ++nt) {
            const short8 bfrag = *(const short8*)(Wpack + (size_t)((kt * NT + nt) * 64 + lane) * 8);
            acc[0][nt] = __builtin_amdgcn_mfma_f32_16x16x32_bf16(a0, bfrag, acc[0][nt], 0, 0, 0);
            acc[1][nt] = __builtin_amdgcn_mfma_f32_16x16x32_bf16(a1, bfrag, acc[1][nt], 0, 0, 0);
        }
    }

#pragma unroll
    for (int nt = 0; nt < NT; ++nt) {
        const float bb = bias[nt * 16 + l16];
#pragma unroll
        for (int s = 0; s < 2; ++s)
#pragma unroll
            for (int rg = 0; rg < 4; ++rg)
                Hs[(wave * 2 + s) * 1024 + (quad * 4 + rg) * 64 + nt * 16 + l16] =
                    (unsigned short)bfr(acc[s][nt][rg] + bb);
    }
    __syncthreads();

    f32x4 sacc[2][2] = {};
#pragma unroll
    for (int s = 0; s < 2; ++s)
#pragma unroll
        for (int kt2 = 0; kt2 < 2; ++kt2) {
            const short8 af = *(const short8*)&Hs[(wave * 2 + s) * 1024 + l16 * 64 +
                                                  kt2 * 32 + quad * 8];
#pragma unroll
            for (int nt2 = 0; nt2 < 2; ++nt2) {
                const short8 bf = *(const short8*)(WpackC + (size_t)((kt2 * 2 + nt2) * 64 + lane) * 8);
                sacc[s][nt2] = __builtin_amdgcn_mfma_f32_16x16x32_bf16(af, bf, sacc[s][nt2], 0, 0, 0);
            }
        }

    const float b1a = bc1[l16], b1b = bc1[16 + l16];
    const float w2a = Wc2[l16], w2b = Wc2[16 + l16];
    const float b2v = bc2[0];
#pragma unroll
    for (int s = 0; s < 2; ++s)
#pragma unroll
        for (int rg = 0; rg < 4; ++rg) {
            float p = fmaxf(sacc[s][0][rg] + b1a, 0.f) * w2a +
                      fmaxf(sacc[s][1][rg] + b1b, 0.f) * w2b;
#pragma unroll
            for (int off = 1; off < 16; off <<= 1) p += __shfl_xor(p, off);
            if (l16 == 0) {
                int row = row_base + s * 16 + quad * 4 + rg;
                if (row < N) out[row] = 1.0f / (1.0f + expf(-(p + b2v)));
            }
        }
}

extern "C" void kernel_launch(void* const* d_in, const int* in_sizes, int n_in,
                              void* d_out, int out_size, void* d_ws, size_t ws_size,
                              hipStream_t stream) {
    const float* x   = (const float*)d_in[0];
    const int*   ei  = (const int*)d_in[1];   // [2, NE] int32
    const int*   src = ei;
    const int*   dst = ei + NE;
    const float* Wl0 = (const float*)d_in[2];
    const float* Wr0 = (const float*)d_in[3];
    const float* b0  = (const float*)d_in[4];
    const float* Wl1 = (const float*)d_in[5];
    const float* Wr1 = (const float*)d_in[6];
    const float* b1  = (const float*)d_in[7];
    const float* Wl2 = (const float*)d_in[8];
    const float* Wr2 = (const float*)d_in[9];
    const float* b2  = (const float*)d_in[10];
    const float* Wc1 = (const float*)d_in[11];
    const float* bc1 = (const float*)d_in[12];
    const float* Wc2 = (const float*)d_in[13];
    const float* bc2 = (const float*)d_in[14];
    float* out = (float*)d_out;

    char*  ws   = (char*)d_ws;
    int*   cnt  = (int*)(ws);
    unsigned short* wp0 = (unsigned short*)(ws + (size_t)256 * 1024);
    unsigned short* wp1 = (unsigned short*)(ws + (size_t)352 * 1024);
    unsigned short* wp2 = (unsigned short*)(ws + (size_t)448 * 1024);
    unsigned short* wpc = (unsigned short*)(ws + (size_t)512 * 1024);
    int*   nbr  = (int*)(ws + (size_t)1 * (1 << 20));
    unsigned short* xb   = (unsigned short*)(ws + (size_t)16 * (1 << 20));
    unsigned short* aggb = (unsigned short*)(ws + (size_t)24 * (1 << 20));
    unsigned short* h0b  = (unsigned short*)(ws + (size_t)40 * (1 << 20));
    unsigned short* h1b  = (unsigned short*)(ws + (size_t)56 * (1 << 20));

    hipMemsetAsync(cnt, 0, (size_t)NN * sizeof(int), stream);

    // ---- try cooperative single-kernel path (grid sized from occupancy) ----
    bool coop_ok = false;
    int maxBpc = 0, ncu = 0, dev = 0;
    hipGetDevice(&dev);
    hipDeviceGetAttribute(&ncu, hipDeviceAttributeMultiprocessorCount, dev);
    hipError_t qerr = hipOccupancyMaxActiveBlocksPerMultiprocessor(
        &maxBpc, (const void*)k_all, 256, 0);
    if (qerr == hipSuccess && maxBpc > 0 && ncu > 0) {
        int grid = maxBpc * ncu;
        if (grid > 2048) grid = 2048;
        const int* srcp = src; const int* dstp = dst;
        void* args[] = {
            (void*)&srcp, (void*)&dstp, (void*)&x,
            (void*)&Wl0, (void*)&Wr0, (void*)&b0,
            (void*)&Wl1, (void*)&Wr1, (void*)&b1,
            (void*)&Wl2, (void*)&Wr2, (void*)&b2,
            (void*)&Wc1, (void*)&bc1, (void*)&Wc2, (void*)&bc2,
            (void*)&cnt, (void*)&nbr, (void*)&xb,
            (void*)&wp0, (void*)&wp1, (void*)&wp2, (void*)&wpc,
            (void*)&aggb, (void*)&h0b, (void*)&h1b,
            (void*)&out
        };
        hipError_t lerr = hipLaunchCooperativeKernel((const void*)k_all, dim3(grid),
                                                     dim3(256), args, 0, stream);
        if (lerr == hipSuccess) coop_ok = true;
        else (void)hipGetLastError();   // clear error state, use fallback
    } else {
        (void)hipGetLastError();
    }

    // ---- fallback: proven R11 multi-kernel pipeline ----
    if (!coop_ok) {
        const int B = 256;
        const int AGG_GRID = (NN + 3) / 4;
        const int MFMA_GRID = (NN + 127) / 128;

        k_prep<<<5889, B, 0, stream>>>(src, dst, cnt, nbr, x, (unsigned*)xb,
                                       Wl0, Wr0, Wl1, Wr1, Wl2, Wr2, Wc1,
                                       wp0, wp1, wp2, wpc);

        k_aggregate<6><<<AGG_GRID, B, 0, stream>>>((const unsigned*)xb, nbr, cnt,
                                                   (unsigned*)aggb, NN);
        k_mfma<64, 128, true><<<MFMA_GRID, B, 0, stream>>>(aggb, xb, wp0, b0, h0b, NN);

        k_aggregate<7><<<AGG_GRID, B, 0, stream>>>((const unsigned*)h0b, nbr, cnt,
                                                   (unsigned*)aggb, NN);
        k_mfma<128, 128, true><<<MFMA_GRID, B, 0, stream>>>(aggb, h0b, wp1, b1, h1b, NN);

        k_aggregate<7><<<AGG_GRID, B, 0, stream>>>((const unsigned*)h1b, nbr, cnt,
                                                   (unsigned*)aggb, NN);
        k_mfma_cls<<<MFMA_GRID, B, 0, stream>>>(aggb, h1b, wp2, wpc, b2, bc1, Wc2, bc2,
                                                out, NN);
    }
}